// Round 4
// baseline (322.877 us; speedup 1.0000x reference)
//
#include <hip/hip_runtime.h>
#include <math.h>

typedef _Float16 half8   __attribute__((ext_vector_type(8)));
typedef _Float16 half4_t __attribute__((ext_vector_type(4)));
typedef float    floatx4  __attribute__((ext_vector_type(4)));
typedef float    floatx16 __attribute__((ext_vector_type(16)));

namespace {

constexpr int S  = 2048;
constexpr int D  = 64;
constexpr int BH = 32;
constexpr int QT = 64;
constexpr int KT = 64;
constexpr int PST = 40;    // P row stride (halves): 80B rows, 16B-aligned, bank-spread
constexpr float INV_T = 0.125f;
constexpr size_t PLANE = (size_t)BH * S * D;
constexpr float MBIAS = 2.772588722239781f;   // 4*ln2 (cancels in O/l)

#define MFMA32(a, b, c) __builtin_amdgcn_mfma_f32_32x32x16_f16((a), (b), (c), 0, 0, 0)
#define MFMA16(a, b, c) __builtin_amdgcn_mfma_f32_16x16x32_f16((a), (b), (c), 0, 0, 0)

typedef __attribute__((address_space(1))) const unsigned int guint;
typedef __attribute__((address_space(3))) unsigned int luint;

__device__ __forceinline__ void gl_lds16(const _Float16* g, _Float16* l) {
    __builtin_amdgcn_global_load_lds((guint*)g, (luint*)l, 16, 0, 0);
}

// ---- fused pre-pass: K -> f16 swizzled [bh][t][d]; V -> f16 transposed [bh][d][s] ----
__global__ __launch_bounds__(256)
void prep_all(const float* __restrict__ kr, const float* __restrict__ ki,
              const float* __restrict__ vr, const float* __restrict__ vi,
              _Float16* __restrict__ okr, _Float16* __restrict__ oki,
              _Float16* __restrict__ ovr, _Float16* __restrict__ ovi)
{
    __shared__ _Float16 tile[64][72];
    const int z  = (int)blockIdx.z;
    const int bh = (int)blockIdx.y, t0 = (int)blockIdx.x * 64;
    const int tid = (int)threadIdx.x;

    if (z < 2) {
        // ---- K path: convert + XOR-chunk swizzle by t&7, natural rows ----
        const float* src = z ? ki : kr;
        _Float16*    dst = z ? oki : okr;
        const int r = tid >> 2, cg = tid & 3;
        const size_t in = ((size_t)bh * S + t0 + r) * D + cg * 16;
        float4 f0 = *(const float4*)(src + in);
        float4 f1 = *(const float4*)(src + in + 4);
        float4 f2 = *(const float4*)(src + in + 8);
        float4 f3 = *(const float4*)(src + in + 12);
        half8 h0, h1;
        h0[0]=(_Float16)f0.x; h0[1]=(_Float16)f0.y; h0[2]=(_Float16)f0.z; h0[3]=(_Float16)f0.w;
        h0[4]=(_Float16)f1.x; h0[5]=(_Float16)f1.y; h0[6]=(_Float16)f1.z; h0[7]=(_Float16)f1.w;
        h1[0]=(_Float16)f2.x; h1[1]=(_Float16)f2.y; h1[2]=(_Float16)f2.z; h1[3]=(_Float16)f2.w;
        h1[4]=(_Float16)f3.x; h1[5]=(_Float16)f3.y; h1[6]=(_Float16)f3.z; h1[7]=(_Float16)f3.w;
        const int key = r & 7;
        const size_t ob = ((size_t)bh * S + t0 + r) * D;
        *(half8*)(dst + ob + ((cg*2    ) ^ key) * 8) = h0;
        *(half8*)(dst + ob + ((cg*2 + 1) ^ key) * 8) = h1;
    } else {
        // ---- V path: LDS transpose (bank-conflict-free writes), swizzle by d&7 ----
        const float* src = (z == 3) ? vi : vr;
        _Float16*    dst = (z == 3) ? ovi : ovr;
        const int r = tid & 63, cg = tid >> 6;   // wave = col-group: LDS row const per wave
        const size_t in = ((size_t)bh * S + t0 + r) * D + cg * 16;
        #pragma unroll
        for (int j = 0; j < 4; ++j) {
            float4 f = *(const float4*)(src + in + j * 4);
            tile[cg*16 + j*4 + 0][r] = (_Float16)f.x;
            tile[cg*16 + j*4 + 1][r] = (_Float16)f.y;
            tile[cg*16 + j*4 + 2][r] = (_Float16)f.z;
            tile[cg*16 + j*4 + 3][r] = (_Float16)f.w;
        }
        __syncthreads();
        const int d = tid >> 2, c2 = tid & 3;
        const int key = d & 7;
        const size_t ob = ((size_t)bh * D + d) * S + t0;
        half8 a = *(const half8*)&tile[d][c2*16];
        half8 b = *(const half8*)&tile[d][c2*16 + 8];
        *(half8*)(dst + ob + ((c2*2    ) ^ key) * 8) = a;
        *(half8*)(dst + ob + ((c2*2 + 1) ^ key) * 8) = b;
    }
}

// ---- main: 32x32x16 MFMA flash complex attention, wave = (q-half, t-half) ----
__global__ __launch_bounds__(256, 2)
void cv_attn_3232(const float* __restrict__ qr_g, const float* __restrict__ qi_g,
                  const _Float16* __restrict__ kh_r, const _Float16* __restrict__ kh_i,
                  const _Float16* __restrict__ vt_r, const _Float16* __restrict__ vt_i,
                  float* __restrict__ out)
{
    // 32KB K/V tiles + 20KB wave-private P = 53248 B
    __shared__ __align__(16) _Float16 sm[4*64*64 + 4*2*32*PST];
    _Float16* const Kr = sm;
    _Float16* const Ki = Kr + 64*64;
    _Float16* const Vr = Ki + 64*64;
    _Float16* const Vi = Vr + 64*64;
    _Float16* const Pb = Vi + 64*64;

    const int tid = (int)threadIdx.x, lane = tid & 63, wv = tid >> 6;
    const int qh = wv & 1, th = wv >> 1;      // q-half, t-half
    const int l5 = lane & 31, h = lane >> 5;

    // XCD-aware decode: one bh per XCD slice (K/V stay L2-local)
    const int b   = (int)blockIdx.x;
    const int xcd = b & 7, y = b >> 3;
    const int qt  = y & 31, bh = xcd + 8 * (y >> 5);
    const int q0  = qt * QT;
    const size_t base = (size_t)bh * S * D;

    _Float16* const Pr = Pb + wv * (2*32*PST);
    _Float16* const Pi = Pr + 32*PST;

    // ---- Q fragments (A: row=lane&31, k=h*8+j + c*16), scaled by 1/T ----
    half8 aqr[4], aqi[4];
    {
        const size_t qoff = base + (size_t)(q0 + qh*32 + l5) * D + h*8;
        #pragma unroll
        for (int c = 0; c < 4; ++c) {
            float4 r0 = *(const float4*)(qr_g + qoff + c*16);
            float4 r1 = *(const float4*)(qr_g + qoff + c*16 + 4);
            float4 i0 = *(const float4*)(qi_g + qoff + c*16);
            float4 i1 = *(const float4*)(qi_g + qoff + c*16 + 4);
            half8 hr, hi;
            hr[0]=(_Float16)(r0.x*INV_T); hr[1]=(_Float16)(r0.y*INV_T);
            hr[2]=(_Float16)(r0.z*INV_T); hr[3]=(_Float16)(r0.w*INV_T);
            hr[4]=(_Float16)(r1.x*INV_T); hr[5]=(_Float16)(r1.y*INV_T);
            hr[6]=(_Float16)(r1.z*INV_T); hr[7]=(_Float16)(r1.w*INV_T);
            hi[0]=(_Float16)(i0.x*INV_T); hi[1]=(_Float16)(i0.y*INV_T);
            hi[2]=(_Float16)(i0.z*INV_T); hi[3]=(_Float16)(i0.w*INV_T);
            hi[4]=(_Float16)(i1.x*INV_T); hi[5]=(_Float16)(i1.y*INV_T);
            hi[6]=(_Float16)(i1.z*INV_T); hi[7]=(_Float16)(i1.w*INV_T);
            aqr[c] = hr; aqi[c] = hi;
        }
    }

    floatx16 Or[2], Oi[2];
    float l_run[16];
    #pragma unroll
    for (int r = 0; r < 16; ++r) l_run[r] = 0.f;
    #pragma unroll
    for (int dt = 0; dt < 2; ++dt) {
        #pragma unroll
        for (int r = 0; r < 16; ++r) { Or[dt][r] = 0.f; Oi[dt][r] = 0.f; }
    }

    const int krow  = th*32 + l5;         // this wave's K-tile row (t)
    const int kbase = krow * 64;
    const int kkey  = l5 & 7;             // = krow & 7

    for (int kt = 0; kt < S/KT; ++kt) {
        const int k0 = kt * KT;
        __syncthreads();

        // async stage: wave w stages one plane (8 x 1KB verbatim, swizzle pre-baked)
        if (wv < 2) {
            const _Float16* src = (wv ? kh_i : kh_r) + ((size_t)bh*S + k0)*D + lane*8;
            _Float16* dst = (wv ? Ki : Kr);
            #pragma unroll
            for (int i = 0; i < 8; ++i)
                gl_lds16(src + i*512, dst + i*512);
        } else {
            const _Float16* src = (wv == 2 ? vt_r : vt_i)
                                + ((size_t)bh*D + (lane>>3))*S + k0 + (lane&7)*8;
            _Float16* dst = (wv == 2 ? Vr : Vi);
            #pragma unroll
            for (int i = 0; i < 8; ++i)
                gl_lds16(src + (size_t)i*8*S, dst + i*512);
        }
        __syncthreads();

        // ---- scores: one 32x32 complex tile per wave (16 MFMAs) ----
        floatx16 Zr, Zi;
        #pragma unroll
        for (int r = 0; r < 16; ++r) { Zr[r] = 0.f; Zi[r] = 0.f; }
        #pragma unroll
        for (int c = 0; c < 4; ++c) {
            const int ck = (((c<<1) | h) ^ kkey) << 3;
            half8 bkr = *(const half8*)&Kr[kbase + ck];
            half8 bki = *(const half8*)&Ki[kbase + ck];
            half8 nki = -bki;
            Zr = MFMA32(aqr[c], bkr, Zr);
            Zr = MFMA32(aqi[c], nki, Zr);     // Zr = QrKr' - QiKi'
            Zi = MFMA32(aqr[c], bki, Zi);
            Zi = MFMA32(aqi[c], bkr, Zi);     // Zi = QrKi' + QiKr'
        }

        // ---- max-free softmax; P (f16) -> wave-private LDS [q][t] ----
        #pragma unroll
        for (int r = 0; r < 16; ++r) {
            const float zr = Zr[r], zi = Zi[r];
            const float s2  = fmaf(zr, zr, fmaf(zi, zi, 1e-24f));
            const float inv = __builtin_amdgcn_rsqf(s2);
            const float mag = s2 * inv;
            const float p   = __expf(mag - MBIAS);
            l_run[r] += p;
            const float w = p * inv;
            const int qrow = (r & 3) + 8*(r >> 2) + 4*h;
            Pr[qrow*PST + l5] = (_Float16)(w * zr);
            Pi[qrow*PST + l5] = (_Float16)(w * zi);
        }
        // P wave-private: no barrier (compiler inserts lgkm waits)

        // ---- PV: O += P * V over this wave's 32 t (16 MFMAs) ----
        #pragma unroll
        for (int c2 = 0; c2 < 2; ++c2) {
            const int po = l5*PST + c2*16 + h*8;
            half8 apr = *(const half8*)&Pr[po];
            half8 api = *(const half8*)&Pi[po];
            half8 nai = -api;
            #pragma unroll
            for (int dt = 0; dt < 2; ++dt) {
                const int vbase = (dt*32 + l5) * 64;
                const int vck = ((th*4 + c2*2 + h) ^ kkey) << 3;   // d&7 == l5&7
                half8 bvr = *(const half8*)&Vr[vbase + vck];
                half8 bvi = *(const half8*)&Vi[vbase + vck];
                Or[dt] = MFMA32(apr, bvr, Or[dt]);
                Or[dt] = MFMA32(nai, bvi, Or[dt]);
                Oi[dt] = MFMA32(apr, bvi, Oi[dt]);
                Oi[dt] = MFMA32(api, bvr, Oi[dt]);
            }
        }
    }

    // ---- epilogue: cross-wave (t-half) reduction, then normalize + store ----
    __syncthreads();
    float* const red = (float*)sm;         // reuse all 53KB; need 40KB
    if (th == 1) {
        float* dst = red + qh * 5120;
        #pragma unroll
        for (int r = 0; r < 16; ++r) {
            dst[(r     )*64 + lane] = Or[0][r];
            dst[(r + 16)*64 + lane] = Or[1][r];
            dst[(r + 32)*64 + lane] = Oi[0][r];
            dst[(r + 48)*64 + lane] = Oi[1][r];
            dst[(r + 64)*64 + lane] = l_run[r];
        }
    }
    __syncthreads();
    if (th == 0) {
        const float* src2 = red + qh * 5120;
        #pragma unroll
        for (int r = 0; r < 16; ++r) {
            Or[0][r] += src2[(r     )*64 + lane];
            Or[1][r] += src2[(r + 16)*64 + lane];
            Oi[0][r] += src2[(r + 32)*64 + lane];
            Oi[1][r] += src2[(r + 48)*64 + lane];
            l_run[r] += src2[(r + 64)*64 + lane];
        }
        // sum l over the 32 t-columns (bits 0..4 only: stays within h-half)
        #pragma unroll
        for (int off = 1; off < 32; off <<= 1)
            #pragma unroll
            for (int r = 0; r < 16; ++r)
                l_run[r] += __shfl_xor(l_run[r], off, 64);

        #pragma unroll
        for (int r = 0; r < 16; ++r) {
            const float linv = 1.0f / l_run[r];
            const int qrow = (r & 3) + 8*(r >> 2) + 4*h;
            const size_t o = base + (size_t)(q0 + qh*32 + qrow) * D + l5;
            out[o]              = Or[0][r] * linv;
            out[o + 32]         = Or[1][r] * linv;
            out[PLANE + o]      = Oi[0][r] * linv;
            out[PLANE + o + 32] = Oi[1][r] * linv;
        }
    }
}

// ---------------- fallback (ws too small): round-2 style, f32 inputs ----------------
constexpr int ST2 = 72;
__global__ __launch_bounds__(256, 2)
void cv_attn_mfma(const float* __restrict__ qr_g, const float* __restrict__ qi_g,
                  const float* __restrict__ kr_g, const float* __restrict__ ki_g,
                  const float* __restrict__ vr_g, const float* __restrict__ vi_g,
                  float* __restrict__ out)
{
    __shared__ __align__(16) _Float16 sm[4*64*ST2 + 4*2*16*ST2];
    _Float16* const Kr = sm;
    _Float16* const Ki = Kr + 64*ST2;
    _Float16* const Vr = Ki + 64*ST2;
    _Float16* const Vi = Vr + 64*ST2;
    _Float16* const Pb = Vi + 64*ST2;

    const int tid = (int)threadIdx.x, lane = tid & 63, wv = tid >> 6;
    const int g = lane >> 4, m = lane & 15;
    const int bh = (int)blockIdx.y;
    const int q0 = (int)blockIdx.x * QT;
    const size_t base = (size_t)bh * S * D;
    _Float16* const Pr = Pb + wv * (2*16*ST2);
    _Float16* const Pi = Pr + 16*ST2;
    const int lofs = m*ST2 + g*8;

    half8 aqr[2], aqi[2], aqin[2];
    {
        const size_t qoff = base + (size_t)(q0 + wv*16 + m) * D + g*8;
        #pragma unroll
        for (int kc = 0; kc < 2; ++kc) {
            float4 r0 = *(const float4*)(qr_g + qoff + kc*32);
            float4 r1 = *(const float4*)(qr_g + qoff + kc*32 + 4);
            float4 i0 = *(const float4*)(qi_g + qoff + kc*32);
            float4 i1 = *(const float4*)(qi_g + qoff + kc*32 + 4);
            half8 hr, hi;
            hr[0]=(_Float16)(r0.x*INV_T); hr[1]=(_Float16)(r0.y*INV_T);
            hr[2]=(_Float16)(r0.z*INV_T); hr[3]=(_Float16)(r0.w*INV_T);
            hr[4]=(_Float16)(r1.x*INV_T); hr[5]=(_Float16)(r1.y*INV_T);
            hr[6]=(_Float16)(r1.z*INV_T); hr[7]=(_Float16)(r1.w*INV_T);
            hi[0]=(_Float16)(i0.x*INV_T); hi[1]=(_Float16)(i0.y*INV_T);
            hi[2]=(_Float16)(i0.z*INV_T); hi[3]=(_Float16)(i0.w*INV_T);
            hi[4]=(_Float16)(i1.x*INV_T); hi[5]=(_Float16)(i1.y*INV_T);
            hi[6]=(_Float16)(i1.z*INV_T); hi[7]=(_Float16)(i1.w*INV_T);
            aqr[kc] = hr; aqi[kc] = hi; aqin[kc] = -hi;
        }
    }

    floatx4 Or[4], Oi[4];
    float m_run[4], l_run[4];
    #pragma unroll
    for (int r = 0; r < 4; ++r) { m_run[r] = -INFINITY; l_run[r] = 0.f; }
    #pragma unroll
    for (int nt = 0; nt < 4; ++nt) {
        Or[nt] = (floatx4){0.f,0.f,0.f,0.f};
        Oi[nt] = (floatx4){0.f,0.f,0.f,0.f};
    }

    for (int kt = 0; kt < S/KT; ++kt) {
        const int k0 = kt * KT;
        __syncthreads();
        if (wv < 2) {
            const float* src = (wv == 0 ? kr_g : ki_g) + base + (size_t)k0 * D;
            _Float16* dst = (wv == 0 ? Kr : Ki);
            #pragma unroll
            for (int it = 0; it < 16; ++it) {
                const int e = it*64 + lane, t = e >> 4, c4 = (e & 15) * 4;
                float4 v = *(const float4*)(src + t*64 + c4);
                half4_t hh = {(_Float16)v.x, (_Float16)v.y, (_Float16)v.z, (_Float16)v.w};
                *(half4_t*)&dst[t*ST2 + c4] = hh;
            }
        } else {
            const float* src = (wv == 2 ? vr_g : vi_g) + base + (size_t)k0 * D;
            _Float16* dst = (wv == 2 ? Vr : Vi);
            #pragma unroll
            for (int t0 = 0; t0 < KT; t0 += 4) {
                float v0 = src[(t0+0)*64 + lane];
                float v1 = src[(t0+1)*64 + lane];
                float v2 = src[(t0+2)*64 + lane];
                float v3 = src[(t0+3)*64 + lane];
                half4_t hh = {(_Float16)v0, (_Float16)v1, (_Float16)v2, (_Float16)v3};
                *(half4_t*)&dst[lane*ST2 + t0] = hh;
            }
        }
        __syncthreads();

        floatx4 Zr[4], Zi[4];
        #pragma unroll
        for (int nt = 0; nt < 4; ++nt) {
            floatx4 zr = (floatx4){0.f,0.f,0.f,0.f};
            floatx4 zi = (floatx4){0.f,0.f,0.f,0.f};
            #pragma unroll
            for (int kc = 0; kc < 2; ++kc) {
                const int o = nt*16*ST2 + lofs + kc*32;
                half8 bkr = *(const half8*)&Kr[o];
                half8 bki = *(const half8*)&Ki[o];
                zr = MFMA16(aqr[kc],  bkr, zr);
                zr = MFMA16(aqin[kc], bki, zr);
                zi = MFMA16(aqr[kc],  bki, zi);
                zi = MFMA16(aqi[kc],  bkr, zi);
            }
            Zr[nt] = zr; Zi[nt] = zi;
        }

        float mag[4][4], mt[4] = {0.f,0.f,0.f,0.f};
        #pragma unroll
        for (int nt = 0; nt < 4; ++nt)
            #pragma unroll
            for (int r = 0; r < 4; ++r) {
                const float a = Zr[nt][r], bz = Zi[nt][r];
                const float s = __builtin_amdgcn_sqrtf(a*a + bz*bz);
                mag[nt][r] = s; mt[r] = fmaxf(mt[r], s);
            }
        #pragma unroll
        for (int off = 1; off < 16; off <<= 1)
            #pragma unroll
            for (int r = 0; r < 4; ++r)
                mt[r] = fmaxf(mt[r], __shfl_xor(mt[r], off, 64));

        float alpha[4], rs[4];
        #pragma unroll
        for (int r = 0; r < 4; ++r) {
            const float mnew = fmaxf(m_run[r], mt[r]);
            alpha[r] = __expf(m_run[r] - mnew);
            m_run[r] = mnew; rs[r] = 0.f;
        }
        #pragma unroll
        for (int nt = 0; nt < 4; ++nt)
            #pragma unroll
            for (int r = 0; r < 4; ++r) {
                const float p = __expf(mag[nt][r] - m_run[r]);
                rs[r] += p;
                const float w = p * __builtin_amdgcn_rcpf(fmaxf(mag[nt][r], 1e-12f));
                Pr[(4*g + r)*ST2 + nt*16 + m] = (_Float16)(w * Zr[nt][r]);
                Pi[(4*g + r)*ST2 + nt*16 + m] = (_Float16)(w * Zi[nt][r]);
            }
        #pragma unroll
        for (int off = 1; off < 16; off <<= 1)
            #pragma unroll
            for (int r = 0; r < 4; ++r)
                rs[r] += __shfl_xor(rs[r], off, 64);
        #pragma unroll
        for (int r = 0; r < 4; ++r) l_run[r] = l_run[r]*alpha[r] + rs[r];

        #pragma unroll
        for (int nt = 0; nt < 4; ++nt)
            #pragma unroll
            for (int r = 0; r < 4; ++r) { Or[nt][r] *= alpha[r]; Oi[nt][r] *= alpha[r]; }

        half8 apr[2], api[2], apin[2];
        #pragma unroll
        for (int kc = 0; kc < 2; ++kc) {
            apr[kc]  = *(const half8*)&Pr[lofs + kc*32];
            api[kc]  = *(const half8*)&Pi[lofs + kc*32];
            apin[kc] = -api[kc];
        }
        #pragma unroll
        for (int nt = 0; nt < 4; ++nt) {
            floatx4 ors = Or[nt], ois = Oi[nt];
            #pragma unroll
            for (int kc = 0; kc < 2; ++kc) {
                const int o = nt*16*ST2 + lofs + kc*32;
                half8 bvr = *(const half8*)&Vr[o];
                half8 bvi = *(const half8*)&Vi[o];
                ors = MFMA16(apr[kc],  bvr, ors);
                ors = MFMA16(apin[kc], bvi, ors);
                ois = MFMA16(apr[kc],  bvi, ois);
                ois = MFMA16(api[kc],  bvr, ois);
            }
            Or[nt] = ors; Oi[nt] = ois;
        }
    }

    #pragma unroll
    for (int r = 0; r < 4; ++r) {
        const float linv = 1.0f / l_run[r];
        const size_t o = base + (size_t)(q0 + wv*16 + 4*g + r) * D + m;
        #pragma unroll
        for (int nt = 0; nt < 4; ++nt) {
            out[o + nt*16]         = Or[nt][r] * linv;
            out[PLANE + o + nt*16] = Oi[nt][r] * linv;
        }
    }
}

} // namespace

extern "C" void kernel_launch(void* const* d_in, const int* in_sizes, int n_in,
                              void* d_out, int out_size, void* d_ws, size_t ws_size,
                              hipStream_t stream) {
    const float* qr = (const float*)d_in[0];
    const float* qi = (const float*)d_in[1];
    const float* kr = (const float*)d_in[2];
    const float* ki = (const float*)d_in[3];
    const float* vr = (const float*)d_in[4];
    const float* vi = (const float*)d_in[5];
    float* out = (float*)d_out;

    const size_t PH = (size_t)BH * S * D;            // halves per ws plane
    const size_t need = 4 * PH * sizeof(_Float16);   // 33.6 MB
    if (ws_size >= need) {
        _Float16* khr = (_Float16*)d_ws;
        _Float16* khi = khr + PH;
        _Float16* vtr = khi + PH;
        _Float16* vti = vtr + PH;
        prep_all<<<dim3(32, 32, 4), 256, 0, stream>>>(kr, ki, vr, vi, khr, khi, vtr, vti);
        cv_attn_3232<<<1024, 256, 0, stream>>>(qr, qi, khr, khi, vtr, vti, out);
    } else {
        cv_attn_mfma<<<dim3(32, 32), 256, 0, stream>>>(qr, qi, kr, ki, vr, vi, out);
    }
}

// Round 5
// 301.716 us; speedup vs baseline: 1.0701x; 1.0701x over previous
//
#include <hip/hip_runtime.h>
#include <math.h>

typedef _Float16 half8   __attribute__((ext_vector_type(8)));
typedef _Float16 half4_t __attribute__((ext_vector_type(4)));
typedef float    floatx4 __attribute__((ext_vector_type(4)));

namespace {

constexpr int S  = 2048;
constexpr int D  = 64;
constexpr int BH = 32;
constexpr int QT = 64;
constexpr int PST = 40;    // P row stride (halves): 80B rows, 16B-aligned
constexpr float INV_T = 0.125f;
constexpr size_t PLANE = (size_t)BH * S * D;
constexpr float MBIAS = 2.772588722239781f;   // 4*ln2 (cancels in O/l)

#define MFMA16(a, b, c) __builtin_amdgcn_mfma_f32_16x16x32_f16((a), (b), (c), 0, 0, 0)

typedef __attribute__((address_space(1))) const unsigned int guint;
typedef __attribute__((address_space(3))) unsigned int luint;

__device__ __forceinline__ void gl_lds16(const _Float16* g, _Float16* l) {
    __builtin_amdgcn_global_load_lds((guint*)g, (luint*)l, 16, 0, 0);
}

// ---- fused pre-pass: K -> f16 swizzled [bh][t][d] (key t&7, 8-chunk rows);
// ----                 V -> f16 transposed [bh][d][s], swizzle within 32-half windows (key d&3)
__global__ __launch_bounds__(256)
void prep_all(const float* __restrict__ kr, const float* __restrict__ ki,
              const float* __restrict__ vr, const float* __restrict__ vi,
              _Float16* __restrict__ okr, _Float16* __restrict__ oki,
              _Float16* __restrict__ ovr, _Float16* __restrict__ ovi)
{
    __shared__ _Float16 tile[64][72];
    const int z  = (int)blockIdx.z;
    const int bh = (int)blockIdx.y, t0 = (int)blockIdx.x * 64;
    const int tid = (int)threadIdx.x;

    if (z < 2) {
        const float* src = z ? ki : kr;
        _Float16*    dst = z ? oki : okr;
        const int r = tid >> 2, cg = tid & 3;
        const size_t in = ((size_t)bh * S + t0 + r) * D + cg * 16;
        float4 f0 = *(const float4*)(src + in);
        float4 f1 = *(const float4*)(src + in + 4);
        float4 f2 = *(const float4*)(src + in + 8);
        float4 f3 = *(const float4*)(src + in + 12);
        half8 h0, h1;
        h0[0]=(_Float16)f0.x; h0[1]=(_Float16)f0.y; h0[2]=(_Float16)f0.z; h0[3]=(_Float16)f0.w;
        h0[4]=(_Float16)f1.x; h0[5]=(_Float16)f1.y; h0[6]=(_Float16)f1.z; h0[7]=(_Float16)f1.w;
        h1[0]=(_Float16)f2.x; h1[1]=(_Float16)f2.y; h1[2]=(_Float16)f2.z; h1[3]=(_Float16)f2.w;
        h1[4]=(_Float16)f3.x; h1[5]=(_Float16)f3.y; h1[6]=(_Float16)f3.z; h1[7]=(_Float16)f3.w;
        const int key = r & 7;
        const size_t ob = ((size_t)bh * S + t0 + r) * D;
        *(half8*)(dst + ob + ((cg*2    ) ^ key) * 8) = h0;
        *(half8*)(dst + ob + ((cg*2 + 1) ^ key) * 8) = h1;
    } else {
        const float* src = (z == 3) ? vi : vr;
        _Float16*    dst = (z == 3) ? ovi : ovr;
        const int r = tid & 63, cg = tid >> 6;   // wave = col-group: conflict-free LDS writes
        const size_t in = ((size_t)bh * S + t0 + r) * D + cg * 16;
        #pragma unroll
        for (int j = 0; j < 4; ++j) {
            float4 f = *(const float4*)(src + in + j * 4);
            tile[cg*16 + j*4 + 0][r] = (_Float16)f.x;
            tile[cg*16 + j*4 + 1][r] = (_Float16)f.y;
            tile[cg*16 + j*4 + 2][r] = (_Float16)f.z;
            tile[cg*16 + j*4 + 3][r] = (_Float16)f.w;
        }
        __syncthreads();
        const int d = tid >> 2, c2 = tid & 3;
        const int key = d & 3;                    // swizzle within 32-half (4-chunk) windows
        const size_t ob = ((size_t)bh * D + d) * S + t0;
        half8 a = *(const half8*)&tile[d][c2*16];
        half8 b = *(const half8*)&tile[d][c2*16 + 8];
        const int j0 = c2*2, j1 = c2*2 + 1;
        *(half8*)(dst + ob + (size_t)(((j0 & 4) | ((j0 & 3) ^ key))) * 8) = a;
        *(half8*)(dst + ob + (size_t)(((j1 & 4) | ((j1 & 3) ^ key))) * 8) = b;
    }
}

// ---- main: 16x16x32 MFMA flash complex attention, KT=32 double-buffered, 1 barrier/tile ----
__global__ __launch_bounds__(256, 3)
void cv_attn_db(const float* __restrict__ qr_g, const float* __restrict__ qi_g,
                const _Float16* __restrict__ kh_r, const _Float16* __restrict__ kh_i,
                const _Float16* __restrict__ vt_r, const _Float16* __restrict__ vt_i,
                float* __restrict__ out)
{
    // 2 bufs x 4 planes x 2048 halves (32KB) + wave-private P (10KB) = 43008 B -> 3 blocks/CU
    __shared__ __align__(16) _Float16 sm[2*4*2048 + 4*2*16*PST];
    _Float16* const Pb = sm + 2*4*2048;

    const int tid = (int)threadIdx.x, lane = tid & 63, wv = tid >> 6;
    const int g = lane >> 4, m = lane & 15;

    // XCD-aware decode: one bh per XCD slice (f16 K/V ~1MB/bh stays L2-local)
    const int b   = (int)blockIdx.x;
    const int xcd = b & 7, y = b >> 3;
    const int qt  = y & 31, bh = xcd + 8 * (y >> 5);
    const int q0  = qt * QT;
    const size_t base = (size_t)bh * S * D;

    _Float16* const Pr = Pb + wv * (2*16*PST);
    _Float16* const Pi = Pr + 16*PST;

    // ---- Q fragments (A: row=m, k=g*8+j + kc*32), scaled by 1/T; Qi negated once ----
    half8 aqr[2], aqi[2], aqin[2];
    {
        const size_t qoff = base + (size_t)(q0 + wv*16 + m) * D + g*8;
        #pragma unroll
        for (int kc = 0; kc < 2; ++kc) {
            float4 r0 = *(const float4*)(qr_g + qoff + kc*32);
            float4 r1 = *(const float4*)(qr_g + qoff + kc*32 + 4);
            float4 i0 = *(const float4*)(qi_g + qoff + kc*32);
            float4 i1 = *(const float4*)(qi_g + qoff + kc*32 + 4);
            half8 hr, hi;
            hr[0]=(_Float16)(r0.x*INV_T); hr[1]=(_Float16)(r0.y*INV_T);
            hr[2]=(_Float16)(r0.z*INV_T); hr[3]=(_Float16)(r0.w*INV_T);
            hr[4]=(_Float16)(r1.x*INV_T); hr[5]=(_Float16)(r1.y*INV_T);
            hr[6]=(_Float16)(r1.z*INV_T); hr[7]=(_Float16)(r1.w*INV_T);
            hi[0]=(_Float16)(i0.x*INV_T); hi[1]=(_Float16)(i0.y*INV_T);
            hi[2]=(_Float16)(i0.z*INV_T); hi[3]=(_Float16)(i0.w*INV_T);
            hi[4]=(_Float16)(i1.x*INV_T); hi[5]=(_Float16)(i1.y*INV_T);
            hi[6]=(_Float16)(i1.z*INV_T); hi[7]=(_Float16)(i1.w*INV_T);
            aqr[kc] = hr; aqi[kc] = hi; aqin[kc] = -hi;
        }
    }

    floatx4 Or[4], Oi[4];
    float l_run[4] = {0.f, 0.f, 0.f, 0.f};
    #pragma unroll
    for (int nt = 0; nt < 4; ++nt) {
        Or[nt] = (floatx4){0.f,0.f,0.f,0.f};
        Oi[nt] = (floatx4){0.f,0.f,0.f,0.f};
    }

    // stage tile kt (32 keys) into buffer bs: wave w stages one plane verbatim (pre-swizzled)
    auto stage = [&](int kt, _Float16* bs) {
        const int k0 = kt * 32;
        if (wv < 2) {
            const _Float16* src = (wv ? kh_i : kh_r) + ((size_t)bh*S + k0)*D + lane*8;
            _Float16* dst = bs + wv*2048;
            #pragma unroll
            for (int i = 0; i < 4; ++i)
                gl_lds16(src + i*512, dst + i*512);
        } else {
            const _Float16* src = (wv == 2 ? vt_r : vt_i)
                                + ((size_t)bh*D + (lane>>2))*S + k0 + (lane&3)*8;
            _Float16* dst = bs + wv*2048;
            #pragma unroll
            for (int i = 0; i < 4; ++i)
                gl_lds16(src + (size_t)i*16*S, dst + i*512);
        }
    };

    auto compute = [&](_Float16* bs) {
        _Float16* const Krt = bs;
        _Float16* const Kit = bs + 2048;
        _Float16* const Vrt = bs + 4096;
        _Float16* const Vit = bs + 6144;

        // ---- scores: Z[16q x 32t] ----
        floatx4 Zr[2], Zi[2];
        #pragma unroll
        for (int nt = 0; nt < 2; ++nt) {
            const int rb  = (nt*16 + m) * 64;
            const int key = m & 7;
            const int ck0 = (g ^ key) * 8, ck1 = ((g + 4) ^ key) * 8;
            half8 bkr0 = *(const half8*)&Krt[rb + ck0];
            half8 bki0 = *(const half8*)&Kit[rb + ck0];
            half8 bkr1 = *(const half8*)&Krt[rb + ck1];
            half8 bki1 = *(const half8*)&Kit[rb + ck1];
            floatx4 zr = (floatx4){0.f,0.f,0.f,0.f};
            floatx4 zi = (floatx4){0.f,0.f,0.f,0.f};
            zr = MFMA16(aqr[0],  bkr0, zr);
            zr = MFMA16(aqin[0], bki0, zr);
            zr = MFMA16(aqr[1],  bkr1, zr);
            zr = MFMA16(aqin[1], bki1, zr);    // Zr = QrKr' - QiKi'
            zi = MFMA16(aqr[0],  bki0, zi);
            zi = MFMA16(aqi[0],  bkr0, zi);
            zi = MFMA16(aqr[1],  bki1, zi);
            zi = MFMA16(aqi[1],  bkr1, zi);    // Zi = QrKi' + QiKr'
            Zr[nt] = zr; Zi[nt] = zi;
        }

        // ---- max-free softmax: p = exp(|z|)*2^-4; P = p*z/|z| -> wave-private LDS [q][t] ----
        #pragma unroll
        for (int nt = 0; nt < 2; ++nt) {
            #pragma unroll
            for (int r = 0; r < 4; ++r) {
                const float zr = Zr[nt][r], zi = Zi[nt][r];
                const float s2  = fmaf(zr, zr, fmaf(zi, zi, 1e-24f));
                const float inv = __builtin_amdgcn_rsqf(s2);
                const float mag = s2 * inv;
                const float p   = __expf(mag - MBIAS);
                l_run[r] += p;
                const float w = p * inv;
                Pr[(4*g + r)*PST + nt*16 + m] = (_Float16)(w * zr);
                Pi[(4*g + r)*PST + nt*16 + m] = (_Float16)(w * zi);
            }
        }
        // P wave-private: compiler inserts lgkm waits, no barrier

        // ---- PV: O += P * V (A = P[16x32], B = Vt rows = d, 32-half windows) ----
        half8 apr = *(const half8*)&Pr[m*PST + g*8];
        half8 api = *(const half8*)&Pi[m*PST + g*8];
        half8 nai = -api;
        #pragma unroll
        for (int nt = 0; nt < 4; ++nt) {
            const int vrb = (nt*16 + m) * 32;
            const int vck = (g ^ (m & 3)) * 8;
            half8 bvr = *(const half8*)&Vrt[vrb + vck];
            half8 bvi = *(const half8*)&Vit[vrb + vck];
            Or[nt] = MFMA16(apr, bvr, Or[nt]);
            Or[nt] = MFMA16(nai, bvi, Or[nt]);
            Oi[nt] = MFMA16(apr, bvi, Oi[nt]);
            Oi[nt] = MFMA16(api, bvr, Oi[nt]);
        }
    };

    _Float16* const buf0 = sm;
    _Float16* const buf1 = sm + 4*2048;

    stage(0, buf0);
    for (int kt = 0; kt < 64; kt += 2) {
        __syncthreads();                    // drains loads into buf0; separates prior compute(buf1)
        stage(kt + 1, buf1);
        compute(buf0);
        __syncthreads();                    // drains loads into buf1; separates compute(buf0)
        if (kt < 62) stage(kt + 2, buf0);
        compute(buf1);
    }

    // ---- deferred l reduction (sum over 16 t-lanes; commutes under max-free scheme) ----
    #pragma unroll
    for (int off = 1; off < 16; off <<= 1)
        #pragma unroll
        for (int r = 0; r < 4; ++r)
            l_run[r] += __shfl_xor(l_run[r], off, 64);

    #pragma unroll
    for (int r = 0; r < 4; ++r) {
        const float linv = 1.0f / l_run[r];
        const size_t o = base + (size_t)(q0 + wv*16 + 4*g + r) * D + m;
        #pragma unroll
        for (int nt = 0; nt < 4; ++nt) {
            out[o + nt*16]         = Or[nt][r] * linv;
            out[PLANE + o + nt*16] = Oi[nt][r] * linv;
        }
    }
}

// ---------------- fallback (ws too small): round-2 style, f32 inputs ----------------
constexpr int ST2 = 72;
__global__ __launch_bounds__(256, 2)
void cv_attn_mfma(const float* __restrict__ qr_g, const float* __restrict__ qi_g,
                  const float* __restrict__ kr_g, const float* __restrict__ ki_g,
                  const float* __restrict__ vr_g, const float* __restrict__ vi_g,
                  float* __restrict__ out)
{
    __shared__ __align__(16) _Float16 sm[4*64*ST2 + 4*2*16*ST2];
    _Float16* const Kr = sm;
    _Float16* const Ki = Kr + 64*ST2;
    _Float16* const Vr = Ki + 64*ST2;
    _Float16* const Vi = Vr + 64*ST2;
    _Float16* const Pb = Vi + 64*ST2;

    const int tid = (int)threadIdx.x, lane = tid & 63, wv = tid >> 6;
    const int g = lane >> 4, m = lane & 15;
    const int bh = (int)blockIdx.y;
    const int q0 = (int)blockIdx.x * QT;
    const size_t base = (size_t)bh * S * D;
    _Float16* const Pr = Pb + wv * (2*16*ST2);
    _Float16* const Pi = Pr + 16*ST2;
    const int lofs = m*ST2 + g*8;

    half8 aqr[2], aqi[2], aqin[2];
    {
        const size_t qoff = base + (size_t)(q0 + wv*16 + m) * D + g*8;
        #pragma unroll
        for (int kc = 0; kc < 2; ++kc) {
            float4 r0 = *(const float4*)(qr_g + qoff + kc*32);
            float4 r1 = *(const float4*)(qr_g + qoff + kc*32 + 4);
            float4 i0 = *(const float4*)(qi_g + qoff + kc*32);
            float4 i1 = *(const float4*)(qi_g + qoff + kc*32 + 4);
            half8 hr, hi;
            hr[0]=(_Float16)(r0.x*INV_T); hr[1]=(_Float16)(r0.y*INV_T);
            hr[2]=(_Float16)(r0.z*INV_T); hr[3]=(_Float16)(r0.w*INV_T);
            hr[4]=(_Float16)(r1.x*INV_T); hr[5]=(_Float16)(r1.y*INV_T);
            hr[6]=(_Float16)(r1.z*INV_T); hr[7]=(_Float16)(r1.w*INV_T);
            hi[0]=(_Float16)(i0.x*INV_T); hi[1]=(_Float16)(i0.y*INV_T);
            hi[2]=(_Float16)(i0.z*INV_T); hi[3]=(_Float16)(i0.w*INV_T);
            hi[4]=(_Float16)(i1.x*INV_T); hi[5]=(_Float16)(i1.y*INV_T);
            hi[6]=(_Float16)(i1.z*INV_T); hi[7]=(_Float16)(i1.w*INV_T);
            aqr[kc] = hr; aqi[kc] = hi; aqin[kc] = -hi;
        }
    }

    floatx4 Or[4], Oi[4];
    float m_run[4], l_run[4];
    #pragma unroll
    for (int r = 0; r < 4; ++r) { m_run[r] = -INFINITY; l_run[r] = 0.f; }
    #pragma unroll
    for (int nt = 0; nt < 4; ++nt) {
        Or[nt] = (floatx4){0.f,0.f,0.f,0.f};
        Oi[nt] = (floatx4){0.f,0.f,0.f,0.f};
    }

    for (int kt = 0; kt < S/64; ++kt) {
        const int k0 = kt * 64;
        __syncthreads();
        if (wv < 2) {
            const float* src = (wv == 0 ? kr_g : ki_g) + base + (size_t)k0 * D;
            _Float16* dst = (wv == 0 ? Kr : Ki);
            #pragma unroll
            for (int it = 0; it < 16; ++it) {
                const int e = it*64 + lane, t = e >> 4, c4 = (e & 15) * 4;
                float4 v = *(const float4*)(src + t*64 + c4);
                half4_t hh = {(_Float16)v.x, (_Float16)v.y, (_Float16)v.z, (_Float16)v.w};
                *(half4_t*)&dst[t*ST2 + c4] = hh;
            }
        } else {
            const float* src = (wv == 2 ? vr_g : vi_g) + base + (size_t)k0 * D;
            _Float16* dst = (wv == 2 ? Vr : Vi);
            #pragma unroll
            for (int t0 = 0; t0 < 64; t0 += 4) {
                float v0 = src[(t0+0)*64 + lane];
                float v1 = src[(t0+1)*64 + lane];
                float v2 = src[(t0+2)*64 + lane];
                float v3 = src[(t0+3)*64 + lane];
                half4_t hh = {(_Float16)v0, (_Float16)v1, (_Float16)v2, (_Float16)v3};
                *(half4_t*)&dst[lane*ST2 + t0] = hh;
            }
        }
        __syncthreads();

        floatx4 Zr[4], Zi[4];
        #pragma unroll
        for (int nt = 0; nt < 4; ++nt) {
            floatx4 zr = (floatx4){0.f,0.f,0.f,0.f};
            floatx4 zi = (floatx4){0.f,0.f,0.f,0.f};
            #pragma unroll
            for (int kc = 0; kc < 2; ++kc) {
                const int o = nt*16*ST2 + lofs + kc*32;
                half8 bkr = *(const half8*)&Kr[o];
                half8 bki = *(const half8*)&Ki[o];
                zr = MFMA16(aqr[kc],  bkr, zr);
                zr = MFMA16(aqin[kc], bki, zr);
                zi = MFMA16(aqr[kc],  bki, zi);
                zi = MFMA16(aqi[kc],  bkr, zi);
            }
            Zr[nt] = zr; Zi[nt] = zi;
        }

        float mag[4][4], mt[4] = {0.f,0.f,0.f,0.f};
        #pragma unroll
        for (int nt = 0; nt < 4; ++nt)
            #pragma unroll
            for (int r = 0; r < 4; ++r) {
                const float a = Zr[nt][r], bz = Zi[nt][r];
                const float s = __builtin_amdgcn_sqrtf(a*a + bz*bz);
                mag[nt][r] = s; mt[r] = fmaxf(mt[r], s);
            }
        #pragma unroll
        for (int off = 1; off < 16; off <<= 1)
            #pragma unroll
            for (int r = 0; r < 4; ++r)
                mt[r] = fmaxf(mt[r], __shfl_xor(mt[r], off, 64));

        float alpha[4], rs[4];
        #pragma unroll
        for (int r = 0; r < 4; ++r) {
            const float mnew = fmaxf(m_run[r], mt[r]);
            alpha[r] = __expf(m_run[r] - mnew);
            m_run[r] = mnew; rs[r] = 0.f;
        }
        #pragma unroll
        for (int nt = 0; nt < 4; ++nt)
            #pragma unroll
            for (int r = 0; r < 4; ++r) {
                const float p = __expf(mag[nt][r] - m_run[r]);
                rs[r] += p;
                const float w = p * __builtin_amdgcn_rcpf(fmaxf(mag[nt][r], 1e-12f));
                Pr[(4*g + r)*ST2 + nt*16 + m] = (_Float16)(w * Zr[nt][r]);
                Pi[(4*g + r)*ST2 + nt*16 + m] = (_Float16)(w * Zi[nt][r]);
            }
        #pragma unroll
        for (int off = 1; off < 16; off <<= 1)
            #pragma unroll
            for (int r = 0; r < 4; ++r)
                rs[r] += __shfl_xor(rs[r], off, 64);
        #pragma unroll
        for (int r = 0; r < 4; ++r) l_run[r] = l_run[r]*alpha[r] + rs[r];

        #pragma unroll
        for (int nt = 0; nt < 4; ++nt)
            #pragma unroll
            for (int r = 0; r < 4; ++r) { Or[nt][r] *= alpha[r]; Oi[nt][r] *= alpha[r]; }

        half8 apr[2], api[2], apin[2];
        #pragma unroll
        for (int kc = 0; kc < 2; ++kc) {
            apr[kc]  = *(const half8*)&Pr[lofs + kc*32];
            api[kc]  = *(const half8*)&Pi[lofs + kc*32];
            apin[kc] = -api[kc];
        }
        #pragma unroll
        for (int nt = 0; nt < 4; ++nt) {
            floatx4 ors = Or[nt], ois = Oi[nt];
            #pragma unroll
            for (int kc = 0; kc < 2; ++kc) {
                const int o = nt*16*ST2 + lofs + kc*32;
                half8 bvr = *(const half8*)&Vr[o];
                half8 bvi = *(const half8*)&Vi[o];
                ors = MFMA16(apr[kc],  bvr, ors);
                ors = MFMA16(apin[kc], bvi, ors);
                ois = MFMA16(apr[kc],  bvi, ois);
                ois = MFMA16(api[kc],  bvr, ois);
            }
            Or[nt] = ors; Oi[nt] = ois;
        }
    }

    #pragma unroll
    for (int r = 0; r < 4; ++r) {
        const float linv = 1.0f / l_run[r];
        const size_t o = base + (size_t)(q0 + wv*16 + 4*g + r) * D + m;
        #pragma unroll
        for (int nt = 0; nt < 4; ++nt) {
            out[o + nt*16]         = Or[nt][r] * linv;
            out[PLANE + o + nt*16] = Oi[nt][r] * linv;
        }
    }
}

} // namespace

extern "C" void kernel_launch(void* const* d_in, const int* in_sizes, int n_in,
                              void* d_out, int out_size, void* d_ws, size_t ws_size,
                              hipStream_t stream) {
    const float* qr = (const float*)d_in[0];
    const float* qi = (const float*)d_in[1];
    const float* kr = (const float*)d_in[2];
    const float* ki = (const float*)d_in[3];
    const float* vr = (const float*)d_in[4];
    const float* vi = (const float*)d_in[5];
    float* out = (float*)d_out;

    const size_t PH = (size_t)BH * S * D;            // halves per ws plane
    const size_t need = 4 * PH * sizeof(_Float16);   // 33.6 MB
    if (ws_size >= need) {
        _Float16* khr = (_Float16*)d_ws;
        _Float16* khi = khr + PH;
        _Float16* vtr = khi + PH;
        _Float16* vti = vtr + PH;
        prep_all<<<dim3(32, 32, 4), 256, 0, stream>>>(kr, ki, vr, vi, khr, khi, vtr, vti);
        cv_attn_db<<<1024, 256, 0, stream>>>(qr, qi, khr, khi, vtr, vti, out);
    } else {
        cv_attn_mfma<<<dim3(32, 32), 256, 0, stream>>>(qr, qi, kr, ki, vr, vi, out);
    }
}